// Round 5
// baseline (361.561 us; speedup 1.0000x reference)
//
#include <hip/hip_runtime.h>

#define N_NODES 100000
#define N_EDGES 1600000
#define D_IN 32
#define D_HID 16
#define D_OUT 2

// dst bucketing: 128 nodes per bucket.
#define NPB 128
#define NB 782                       // ceil(100000/128)
#define NROWS (NB * NPB)             // 100096 padded feature rows
#define CHUNK 4096
#define BBLOCKS ((N_EDGES + CHUNK - 1) / CHUNK)   // 391

// Padded per-bucket record windows (mean fill 2046, 11 sigma headroom).
#define PBC 2560
#define DUMMY_SRC 100000u            // zeroed xr feature row; hr[100000]=0
#define DUMMY_REC ((127u << 17) | DUMMY_SRC)
#define RPT 10                       // records per thread(-pair): PBC/256

__device__ __forceinline__ unsigned bfr(float x) {   // f32 -> bf16 (RNE)
    unsigned u = __float_as_uint(x);
    return (u + 0x7FFFu + ((u >> 16) & 1u)) >> 16;
}
__device__ __forceinline__ float bfu(unsigned lo16) {
    return __uint_as_float(lo16 << 16);
}

// Native LDS float atomic add (fire-and-forget ds_add_f32).
// !! Compiler does NOT track lgkmcnt for inline-asm DS ops: every ldsAdd
// region MUST be followed by ldsFence() before the publishing barrier
// (round-3 post-mortem: lost updates, absmax 32.75).
// !! Issue ALL independent global loads BEFORE the first ldsAdd: the
// "memory" clobber pins ordering, and interleaving load->add per record
// collapses MLP to 1 (round-2/4 post-mortem: 174 µs at 1% VALU).
__device__ __forceinline__ void ldsAdd(float* p, float v) {
    unsigned off = (unsigned)(size_t)(__attribute__((address_space(3))) float*)p;
    asm volatile("ds_add_f32 %0, %1" :: "v"(off), "v"(v) : "memory");
}
__device__ __forceinline__ void ldsFence() {
    asm volatile("s_waitcnt lgkmcnt(0)" ::: "memory");
}

// ---------------------------------------------------------------------------
// Fused bin + node-1 transform with bucket-grouped coalesced write-out.
// (UNCHANGED from verified 162.8 µs kernel.)
// ---------------------------------------------------------------------------
__global__ __launch_bounds__(512) void k_bin_node1(
    const int* __restrict__ ei, const float* __restrict__ x,
    const float* __restrict__ w_rel, const float* __restrict__ w_root,
    const float* __restrict__ bb,
    unsigned short* __restrict__ xr, float* __restrict__ agg,
    int* __restrict__ gcur, unsigned* __restrict__ recs2)
{
    __shared__ int cnt[NB];
    __shared__ int lcnt[NB];
    __shared__ int loff[NB];
    __shared__ int gbase[NB];
    __shared__ unsigned sorted[CHUNK];           // 16 KB
    __shared__ unsigned short bkt16[CHUNK];      // 8 KB
    __shared__ float s_rel[D_HID * D_IN];
    __shared__ float s_root[D_HID * D_IN];
    __shared__ float s_b[D_HID];
    int blk = blockIdx.x, tid = threadIdx.x;

    for (int i = tid; i < D_HID * D_IN; i += 512) {
        s_rel[i]  = w_rel[i];
        s_root[i] = w_root[i];
    }
    if (tid < D_HID) s_b[tid] = bb[tid];
    for (int i = tid; i < NB; i += 512) { cnt[i] = 0; lcnt[i] = 0; }
    __syncthreads();

    // ---- phase A: histogram ----
    int e0 = blk * CHUNK;
    int e1 = min(e0 + CHUNK, N_EDGES);
    for (int e = e0 + tid; e < e1; e += 512)
        atomicAdd(&cnt[ei[N_EDGES + e] >> 7], 1);

    // ---- phase B: node-1 transform (independent of A) ----
    int node = blk * 512 + tid;                    // 391*512 = 200192 > 100001
    if (node == N_NODES) {                         // dummy zero xr row
        uint4* xp = (uint4*)(xr + (size_t)node * D_HID);
        xp[0] = make_uint4(0, 0, 0, 0);
        xp[1] = make_uint4(0, 0, 0, 0);
    } else if (node < N_NODES) {
        float row[D_IN];
        const float4* xp = (const float4*)(x + (size_t)node * D_IN);
#pragma unroll
        for (int i = 0; i < D_IN / 4; i++) {
            float4 v = xp[i];
            row[4*i+0] = v.x; row[4*i+1] = v.y; row[4*i+2] = v.z; row[4*i+3] = v.w;
        }
        float oa[D_HID], orr[D_HID];
#pragma unroll
        for (int o = 0; o < D_HID; o++) {
            float a = 0.f, r = s_b[o];
#pragma unroll
            for (int k = 0; k < D_IN; k++) {
                a += row[k] * s_rel[o * D_IN + k];
                r += row[k] * s_root[o * D_IN + k];
            }
            oa[o] = a; orr[o] = r;
        }
        unsigned p[8];
#pragma unroll
        for (int i = 0; i < 8; i++)
            p[i] = bfr(oa[2*i]) | (bfr(oa[2*i+1]) << 16);
        uint4* xrp = (uint4*)(xr + (size_t)node * D_HID);
        xrp[0] = make_uint4(p[0], p[1], p[2], p[3]);
        xrp[1] = make_uint4(p[4], p[5], p[6], p[7]);
        float4* aggp = (float4*)(agg + (size_t)node * D_HID);
#pragma unroll
        for (int i = 0; i < D_HID / 4; i++)
            aggp[i] = make_float4(orr[4*i], orr[4*i+1], orr[4*i+2], orr[4*i+3]);
    }
    __syncthreads();

    // ---- phase C: scan (wave 0) || global reservation (waves 1-7) ----
    if (tid < 64) {
        int running = 0;
        for (int c = 0; c < (NB + 63) / 64; c++) {
            int idx = c * 64 + tid;
            int v = (idx < NB) ? cnt[idx] : 0;
            int incl = v;
#pragma unroll
            for (int off = 1; off < 64; off <<= 1) {
                int t = __shfl_up(incl, off);
                if (tid >= off) incl += t;
            }
            if (idx < NB) loff[idx] = running + incl - v;
            running += __shfl(incl, 63);
        }
    } else {
        for (int i = tid - 64; i < NB; i += 448)
            gbase[i] = (cnt[i] > 0) ? atomicAdd(&gcur[i], cnt[i]) : 0;
    }
    __syncthreads();

    // ---- phase D1: placement, grouped by bucket in LDS ----
    for (int e = e0 + tid; e < e1; e += 512) {
        int src = ei[e];
        int dst = ei[N_EDGES + e];
        int bkt = dst >> 7;
        int r = atomicAdd(&lcnt[bkt], 1);
        int p = loff[bkt] + r;
        sorted[p] = ((unsigned)(dst & (NPB - 1)) << 17) | (unsigned)src;
        bkt16[p] = (unsigned short)bkt;
    }
    __syncthreads();

    // ---- phase D2: linear write-out (coalesced runs per bucket) ----
    int n4 = e1 - e0;
    for (int i = tid; i < n4; i += 512) {
        int b = bkt16[i];
        int idx = gbase[b] + (i - loff[b]);
        if (idx < PBC)                             // 11-sigma overflow guard
            recs2[b * PBC + idx] = sorted[i];
    }
}

// ---------------------------------------------------------------------------
// Layer-1 accumulate + ReLU + layer-2 weight fold, one block per bucket.
// MLP-restructured: each thread-pair batch-loads its 10 records, issues 10
// INDEPENDENT uint4 bf16 gathers, then does all 80 ds_add_f32. Guarded tail
// records read the zeroed dummy xr row (adds +0.0 to tile row 127).
// ---------------------------------------------------------------------------
__global__ __launch_bounds__(512) void k_agg1x(
    const int* __restrict__ gcur, const unsigned* __restrict__ recs2,
    const unsigned short* __restrict__ xr, const float* __restrict__ agg,
    const float* __restrict__ w_rel2, const float* __restrict__ w_root2,
    const float* __restrict__ bb2,
    float* __restrict__ hr, float* __restrict__ outv)
{
    __shared__ float tile[NPB][D_HID + 1];       // stride 17 -> banks spread
    __shared__ float s_rel[D_OUT * D_HID];
    __shared__ float s_root[D_OUT * D_HID];
    __shared__ float s_b[D_OUT];
    int b = blockIdx.x, tid = threadIdx.x;

    // ---- issue record loads + gathers FIRST (deep MLP, hide under init) ----
    int n = min(gcur[b], PBC);
    const unsigned* rp = recs2 + (size_t)b * PBC;
    int half = tid & 1;
    int p = tid >> 1;                             // 0..255
    unsigned e[RPT];
#pragma unroll
    for (int k = 0; k < RPT; k++) {
        int idx = p + k * 256;
        e[k] = (idx < n) ? rp[idx] : DUMMY_REC;
    }
    uint4 v[RPT];
#pragma unroll
    for (int k = 0; k < RPT; k++)
        v[k] = *(const uint4*)(xr + (size_t)(e[k] & 0x1FFFF) * D_HID + half * 8);

    if (tid < D_OUT * D_HID) {
        s_rel[tid]  = w_rel2[tid];
        s_root[tid] = w_root2[tid];
    }
    if (tid < D_OUT) s_b[tid] = bb2[tid];

    // ---- load root tile (one float4 per thread: 512*4 = 2048 floats) ----
    {
        int i4 = tid * 4;
        float4 t = *(const float4*)(agg + (size_t)b * NPB * D_HID + i4);
        int r = i4 >> 4, c = i4 & 15;
        tile[r][c + 0] = t.x; tile[r][c + 1] = t.y;
        tile[r][c + 2] = t.z; tile[r][c + 3] = t.w;
    }
    __syncthreads();

    // ---- all LDS atomic adds (loads already in flight / complete) ----
#pragma unroll
    for (int k = 0; k < RPT; k++) {
        float* d = &tile[e[k] >> 17][half * 8];
        ldsAdd(d + 0, bfu(v[k].x & 0xFFFFu)); ldsAdd(d + 1, bfu(v[k].x >> 16));
        ldsAdd(d + 2, bfu(v[k].y & 0xFFFFu)); ldsAdd(d + 3, bfu(v[k].y >> 16));
        ldsAdd(d + 4, bfu(v[k].z & 0xFFFFu)); ldsAdd(d + 5, bfu(v[k].z >> 16));
        ldsAdd(d + 6, bfu(v[k].w & 0xFFFFu)); ldsAdd(d + 7, bfu(v[k].w >> 16));
    }
    ldsFence();        // drain this wave's asm ds_adds BEFORE the barrier
    __syncthreads();

    // ---- ReLU + layer-2 fold, write hr and outv root part ----
    if (tid < NPB) {
        int node = b * NPB + tid;
        if (node < N_NODES) {
            float h[D_HID];
#pragma unroll
            for (int k = 0; k < D_HID; k++) h[k] = fmaxf(tile[tid][k], 0.f);
            float o_rel[D_OUT], o_root[D_OUT];
#pragma unroll
            for (int o = 0; o < D_OUT; o++) {
                float a = 0.f, r = s_b[o];
#pragma unroll
                for (int k = 0; k < D_HID; k++) {
                    a += h[k] * s_rel[o * D_HID + k];
                    r += h[k] * s_root[o * D_HID + k];
                }
                o_rel[o] = a; o_root[o] = r;
            }
            ((float2*)hr)[node]   = make_float2(o_rel[0], o_rel[1]);
            ((float2*)outv)[node] = make_float2(o_root[0], o_root[1]);
        }
    }
    // dummy hr row consumed by k_acc2x's guarded tail gathers
    if (b == 0 && tid == 256)
        ((float2*)hr)[N_NODES] = make_float2(0.f, 0.f);
}

// ---------------------------------------------------------------------------
// Layer-2 accumulate, one block per bucket, same MLP-batched structure:
// 10 record loads, 10 independent float2 hr gathers (L2-resident), then all
// 20 ds_adds into the outv tile (stride 3), fence+barrier, plain store back.
// ---------------------------------------------------------------------------
__global__ __launch_bounds__(256) void k_acc2x(
    const int* __restrict__ gcur, const unsigned* __restrict__ recs2,
    const float* __restrict__ hr, float* __restrict__ outv)
{
    __shared__ float tile[NPB * 3];              // stride 3 per node
    int b = blockIdx.x, tid = threadIdx.x;
    int n = min(gcur[b], PBC);
    const unsigned* rp = recs2 + (size_t)b * PBC;

    unsigned e[RPT];
#pragma unroll
    for (int k = 0; k < RPT; k++) {
        int idx = tid + k * 256;
        e[k] = (idx < n) ? rp[idx] : DUMMY_REC;
    }
    float2 v[RPT];
#pragma unroll
    for (int k = 0; k < RPT; k++)
        v[k] = ((const float2*)hr)[e[k] & 0x1FFFF];

    if (tid < NPB) {
        int node = b * NPB + tid;
        if (node < N_NODES) {
            float2 o = ((const float2*)outv)[node];
            tile[tid * 3 + 0] = o.x;
            tile[tid * 3 + 1] = o.y;
        }
    }
    __syncthreads();

#pragma unroll
    for (int k = 0; k < RPT; k++) {
        int d3 = (int)(e[k] >> 17) * 3;
        ldsAdd(&tile[d3 + 0], v[k].x);
        ldsAdd(&tile[d3 + 1], v[k].y);
    }
    ldsFence();        // drain this wave's asm ds_adds BEFORE the barrier
    __syncthreads();

    if (tid < NPB) {
        int node = b * NPB + tid;
        if (node < N_NODES)
            ((float2*)outv)[node] = make_float2(tile[tid * 3], tile[tid * 3 + 1]);
    }
}

extern "C" void kernel_launch(void* const* d_in, const int* in_sizes, int n_in,
                              void* d_out, int out_size, void* d_ws, size_t ws_size,
                              hipStream_t stream) {
    const float* x       = (const float*)d_in[0];
    const int*   ei      = (const int*)  d_in[1];
    const float* w1_rel  = (const float*)d_in[2];
    const float* w1_root = (const float*)d_in[3];
    const float* b1      = (const float*)d_in[4];
    const float* w2_rel  = (const float*)d_in[5];
    const float* w2_root = (const float*)d_in[6];
    const float* b2      = (const float*)d_in[7];
    float* out = (float*)d_out;

    // Workspace (~18.5 MB; everything rewritten each call):
    float*          agg   = (float*)d_ws;                                   // NROWS*16 f32 (6.4 MB)
    unsigned short* xrh   = (unsigned short*)(agg + (size_t)NROWS * D_HID); // NROWS*16 bf16 (3.2 MB)
    unsigned*       recs2 = (unsigned*)(xrh + (size_t)NROWS * D_HID);       // NB*PBC (8.0 MB)
    float*          hr    = (float*)(recs2 + (size_t)NB * PBC);             // NROWS*2 f32 (0.8 MB)
    int*            gcur  = (int*)(hr + (size_t)NROWS * D_OUT);             // NB

    hipMemsetAsync(gcur, 0, NB * sizeof(int), stream);

    k_bin_node1<<<dim3(BBLOCKS), dim3(512), 0, stream>>>(
        ei, x, w1_rel, w1_root, b1, xrh, agg, gcur, recs2);

    k_agg1x<<<dim3(NB), dim3(512), 0, stream>>>(
        gcur, recs2, xrh, agg, w2_rel, w2_root, b2, hr, out);

    k_acc2x<<<dim3(NB), dim3(256), 0, stream>>>(gcur, recs2, hr, out);
}

// Round 6
// 160.893 us; speedup vs baseline: 2.2472x; 2.2472x over previous
//
#include <hip/hip_runtime.h>

#define N_NODES 100000
#define N_EDGES 1600000
#define D_IN 32
#define D_HID 16
#define D_OUT 2

// dst bucketing: 128 nodes per bucket.
#define NPB 128
#define NB 782                       // ceil(100000/128)
#define NROWS (NB * NPB)             // 100096 padded feature rows
#define CHUNK 4096
#define BBLOCKS ((N_EDGES + CHUNK - 1) / CHUNK)   // 391

// Padded per-bucket record windows (mean fill 2046, 11 sigma headroom).
#define PBC 2560
#define DUMMY_SRC 100000u            // zeroed xr feature row; hr[100000]=0
#define DUMMY_REC ((127u << 17) | DUMMY_SRC)
#define PAD_ALIGN 16

// Layer-2 acc: 2 lanes/record, ACC2_K records per group, 128 groups/block.
#define ACC2_K 16
#define ACC2_BPB 2                     // 2*128*16 = 4096 slots >= PBC
#define ACC2_BLOCKS (NB * ACC2_BPB)    // 1564

// LESSON (rounds 2-5): LDS f32 atomics (ds_add_f32, or atomicAdd on
// __shared__) execute at ~4.2 cycles PER LANE (~267 cyc per wave64 op) on
// gfx950 — three different tile-scatter implementations all landed at
// 174-218 µs with every pipe <2% busy. Bulk scatter-accumulate must use
// sort + register run-combining + sparse GLOBAL atomics (this file's
// structure), never LDS atomics.

__device__ __forceinline__ unsigned bfr(float x) {   // f32 -> bf16 (RNE)
    unsigned u = __float_as_uint(x);
    return (u + 0x7FFFu + ((u >> 16) & 1u)) >> 16;
}
__device__ __forceinline__ float bfu(unsigned lo16) {
    return __uint_as_float(lo16 << 16);
}

// ---------------------------------------------------------------------------
// Fused bin + node-1 transform with bucket-grouped coalesced write-out.
// (UNCHANGED from verified 162.8 µs kernel.)
// ---------------------------------------------------------------------------
__global__ __launch_bounds__(512) void k_bin_node1(
    const int* __restrict__ ei, const float* __restrict__ x,
    const float* __restrict__ w_rel, const float* __restrict__ w_root,
    const float* __restrict__ bb,
    unsigned short* __restrict__ xr, float* __restrict__ agg,
    int* __restrict__ gcur, unsigned* __restrict__ recs2)
{
    __shared__ int cnt[NB];
    __shared__ int lcnt[NB];
    __shared__ int loff[NB];
    __shared__ int gbase[NB];
    __shared__ unsigned sorted[CHUNK];           // 16 KB
    __shared__ unsigned short bkt16[CHUNK];      // 8 KB
    __shared__ float s_rel[D_HID * D_IN];
    __shared__ float s_root[D_HID * D_IN];
    __shared__ float s_b[D_HID];
    int blk = blockIdx.x, tid = threadIdx.x;

    for (int i = tid; i < D_HID * D_IN; i += 512) {
        s_rel[i]  = w_rel[i];
        s_root[i] = w_root[i];
    }
    if (tid < D_HID) s_b[tid] = bb[tid];
    for (int i = tid; i < NB; i += 512) { cnt[i] = 0; lcnt[i] = 0; }
    __syncthreads();

    // ---- phase A: histogram ----
    int e0 = blk * CHUNK;
    int e1 = min(e0 + CHUNK, N_EDGES);
    for (int e = e0 + tid; e < e1; e += 512)
        atomicAdd(&cnt[ei[N_EDGES + e] >> 7], 1);

    // ---- phase B: node-1 transform (independent of A) ----
    int node = blk * 512 + tid;                    // 391*512 = 200192 > 100001
    if (node == N_NODES) {                         // dummy zero xr row
        uint4* xp = (uint4*)(xr + (size_t)node * D_HID);
        xp[0] = make_uint4(0, 0, 0, 0);
        xp[1] = make_uint4(0, 0, 0, 0);
    } else if (node < N_NODES) {
        float row[D_IN];
        const float4* xp = (const float4*)(x + (size_t)node * D_IN);
#pragma unroll
        for (int i = 0; i < D_IN / 4; i++) {
            float4 v = xp[i];
            row[4*i+0] = v.x; row[4*i+1] = v.y; row[4*i+2] = v.z; row[4*i+3] = v.w;
        }
        float oa[D_HID], orr[D_HID];
#pragma unroll
        for (int o = 0; o < D_HID; o++) {
            float a = 0.f, r = s_b[o];
#pragma unroll
            for (int k = 0; k < D_IN; k++) {
                a += row[k] * s_rel[o * D_IN + k];
                r += row[k] * s_root[o * D_IN + k];
            }
            oa[o] = a; orr[o] = r;
        }
        unsigned p[8];
#pragma unroll
        for (int i = 0; i < 8; i++)
            p[i] = bfr(oa[2*i]) | (bfr(oa[2*i+1]) << 16);
        uint4* xrp = (uint4*)(xr + (size_t)node * D_HID);
        xrp[0] = make_uint4(p[0], p[1], p[2], p[3]);
        xrp[1] = make_uint4(p[4], p[5], p[6], p[7]);
        float4* aggp = (float4*)(agg + (size_t)node * D_HID);
#pragma unroll
        for (int i = 0; i < D_HID / 4; i++)
            aggp[i] = make_float4(orr[4*i], orr[4*i+1], orr[4*i+2], orr[4*i+3]);
    }
    __syncthreads();

    // ---- phase C: scan (wave 0) || global reservation (waves 1-7) ----
    if (tid < 64) {
        int running = 0;
        for (int c = 0; c < (NB + 63) / 64; c++) {
            int idx = c * 64 + tid;
            int v = (idx < NB) ? cnt[idx] : 0;
            int incl = v;
#pragma unroll
            for (int off = 1; off < 64; off <<= 1) {
                int t = __shfl_up(incl, off);
                if (tid >= off) incl += t;
            }
            if (idx < NB) loff[idx] = running + incl - v;
            running += __shfl(incl, 63);
        }
    } else {
        for (int i = tid - 64; i < NB; i += 448)
            gbase[i] = (cnt[i] > 0) ? atomicAdd(&gcur[i], cnt[i]) : 0;
    }
    __syncthreads();

    // ---- phase D1: placement, grouped by bucket in LDS ----
    for (int e = e0 + tid; e < e1; e += 512) {
        int src = ei[e];
        int dst = ei[N_EDGES + e];
        int bkt = dst >> 7;
        int r = atomicAdd(&lcnt[bkt], 1);
        int p = loff[bkt] + r;
        sorted[p] = ((unsigned)(dst & (NPB - 1)) << 17) | (unsigned)src;
        bkt16[p] = (unsigned short)bkt;
    }
    __syncthreads();

    // ---- phase D2: linear write-out (coalesced runs per bucket) ----
    int n4 = e1 - e0;
    for (int i = tid; i < n4; i += 512) {
        int b = bkt16[i];
        int idx = gbase[b] + (i - loff[b]);
        if (idx < PBC)                             // 11-sigma overflow guard
            recs2[b * PBC + idx] = sorted[i];
    }
}

// ---------------------------------------------------------------------------
// Fused per-bucket sort + layer-1 accumulate + ReLU + layer-2 weight fold:
//  1. stage the bucket window in LDS (coalesced read)
//  2. counting-sort by (dst&127) into a second LDS array, pad to 16
//  3. write sorted records back coalesced (consumed later by k_acc2)
//  4. accumulate: 32 groups x 16 lanes, 16-record register chunks from LDS,
//     16 independent bf16 line-gathers in flight, run-combining, atomic
//     flush into agg (~200 flushes/bucket)
//  5. NEW (fuses old k_node2h): block b owns agg rows b*128..+127, and all
//     of its atomic flushes drained at the pre-barrier vmcnt(0) — so after
//     __syncthreads() read the tile back, h=relu(agg row), write
//     hr = h@w2_rel^T and outv = h@w2_root^T + b2 directly.
// ---------------------------------------------------------------------------
__global__ __launch_bounds__(512) void k_sortacc(
    const int* __restrict__ gcur, unsigned* __restrict__ recs2,
    const unsigned short* __restrict__ srcf, float* __restrict__ dstf,
    const float* __restrict__ w_rel2, const float* __restrict__ w_root2,
    const float* __restrict__ bb2,
    float* __restrict__ hr, float* __restrict__ outv)
{
    __shared__ unsigned stage[PBC];
    __shared__ unsigned sorted[PBC];
    __shared__ int hist[NPB], sc[NPB], cur[NPB];
    __shared__ float s_rel2[D_OUT * D_HID];
    __shared__ float s_root2[D_OUT * D_HID];
    __shared__ float s_b2[D_OUT];
    int b = blockIdx.x, tid = threadIdx.x;
    int n = min(gcur[b], PBC);
    unsigned* w = recs2 + (size_t)b * PBC;

    if (tid < D_OUT * D_HID) {
        s_rel2[tid]  = w_rel2[tid];
        s_root2[tid] = w_root2[tid];
    }
    if (tid < D_OUT) s_b2[tid] = bb2[tid];

    if (tid < NPB) hist[tid] = 0;
    for (int i = tid; i < n; i += 512) stage[i] = w[i];
    __syncthreads();
    for (int i = tid; i < n; i += 512)
        atomicAdd(&hist[stage[i] >> 17], 1);
    __syncthreads();
    if (tid < NPB) sc[tid] = hist[tid];
    __syncthreads();
#pragma unroll
    for (int off = 1; off < NPB; off <<= 1) {
        int t = (tid >= off && tid < NPB) ? sc[tid - off] : 0;
        __syncthreads();
        if (tid < NPB) sc[tid] += t;
        __syncthreads();
    }
    if (tid < NPB) cur[tid] = sc[tid] - hist[tid];
    __syncthreads();
    for (int i = tid; i < n; i += 512) {
        unsigned r = stage[i];
        int slot = atomicAdd(&cur[r >> 17], 1);
        sorted[slot] = r;
    }
    int npad = (n + PAD_ALIGN - 1) & ~(PAD_ALIGN - 1);
    for (int i = n + tid; i < npad; i += 512) sorted[i] = DUMMY_REC;
    __syncthreads();

    // write back sorted (sequential, coalesced) for k_acc2
    for (int i = tid; i < npad; i += 512) w[i] = sorted[i];

    // layer-1 accumulate straight from LDS
    int g = tid >> 4;                 // 0..31
    int f = tid & (D_HID - 1);
    int dbase = b * NPB;
    for (int base = g * 16; base < npad; base += 32 * 16) {
        unsigned e[16];
#pragma unroll
        for (int k = 0; k < 16; k++) e[k] = sorted[base + k];
        float v[16];
#pragma unroll
        for (int k = 0; k < 16; k++)
            v[k] = bfu(srcf[(e[k] & 0x1FFFF) * D_HID + f]);

        unsigned curd = e[0] >> 17;
        float acc = v[0];
#pragma unroll
        for (int k = 1; k < 16; k++) {
            unsigned dl = e[k] >> 17;
            if (dl == curd) {
                acc += v[k];
            } else {
                atomicAdd(&dstf[(dbase + curd) * D_HID + f], acc);
                curd = dl;
                acc = v[k];
            }
        }
        atomicAdd(&dstf[(dbase + curd) * D_HID + f], acc);
    }

    // ---- fused node-2 fold (was k_node2h) ----
    // All block atomics to dstf drained at the barrier (vmcnt(0)); block b
    // exclusively owns rows dbase..dbase+127, so the readback is coherent.
    __syncthreads();
    if (tid < NPB) {
        int node = dbase + tid;
        if (node < N_NODES) {
            float h[D_HID];
            const float4* ap = (const float4*)(dstf + (size_t)node * D_HID);
#pragma unroll
            for (int i = 0; i < D_HID / 4; i++) {
                float4 vv = ap[i];
                h[4*i+0] = fmaxf(vv.x, 0.f); h[4*i+1] = fmaxf(vv.y, 0.f);
                h[4*i+2] = fmaxf(vv.z, 0.f); h[4*i+3] = fmaxf(vv.w, 0.f);
            }
            float o_rel[D_OUT], o_root[D_OUT];
#pragma unroll
            for (int o = 0; o < D_OUT; o++) {
                float a = 0.f, r = s_b2[o];
#pragma unroll
                for (int k = 0; k < D_HID; k++) {
                    a += h[k] * s_rel2[o * D_HID + k];
                    r += h[k] * s_root2[o * D_HID + k];
                }
                o_rel[o] = a; o_root[o] = r;
            }
            ((float2*)hr)[node]   = make_float2(o_rel[0], o_rel[1]);
            ((float2*)outv)[node] = make_float2(o_root[0], o_root[1]);
        } else if (node == N_NODES) {
            // dummy hr row consumed by k_acc2's tail/dummy gathers
            ((float2*)hr)[node] = make_float2(0.f, 0.f);
        }
    }
}

// ---------------------------------------------------------------------------
// Layer-2 accumulate: 2 lanes/record, ACC2_K=16 records/group, float2 hr
// gathers (0.8 MB, L2-resident), run-combining, flushes straight into out.
// Dummy/tail recs map to row >= N_NODES in last bucket -> bounds-guarded;
// elsewhere they contribute hr[DUMMY_SRC] = 0.
// (UNCHANGED from verified 162.8 µs kernel.)
// ---------------------------------------------------------------------------
__global__ __launch_bounds__(256) void k_acc2(
    const unsigned* __restrict__ recs2, const int* __restrict__ gcur,
    const float* __restrict__ hr, float* __restrict__ outv)
{
    int bucket = blockIdx.x / ACC2_BPB;
    int blk    = blockIdx.x % ACC2_BPB;
    int g = threadIdx.x >> 1;
    int f = threadIdx.x & 1;
    int r0 = (blk * 128 + g) * ACC2_K;
    int n = min(gcur[bucket], PBC);
    if (r0 >= n) return;
    const unsigned* rp = recs2 + (size_t)bucket * PBC + r0;

    unsigned e[ACC2_K];
#pragma unroll
    for (int k = 0; k < ACC2_K; k++) e[k] = rp[k];
    float v[ACC2_K];
#pragma unroll
    for (int k = 0; k < ACC2_K; k++)
        v[k] = hr[(e[k] & 0x1FFFF) * D_OUT + f];

    int dbase = bucket * NPB;
    unsigned cur = e[0] >> 17;
    float acc = v[0];
#pragma unroll
    for (int k = 1; k < ACC2_K; k++) {
        unsigned dl = e[k] >> 17;
        if (dl == cur) {
            acc += v[k];
        } else {
            int d = dbase + (int)cur;
            if (d < N_NODES) atomicAdd(&outv[d * D_OUT + f], acc);
            cur = dl;
            acc = v[k];
        }
    }
    int d = dbase + (int)cur;
    if (d < N_NODES) atomicAdd(&outv[d * D_OUT + f], acc);
}

extern "C" void kernel_launch(void* const* d_in, const int* in_sizes, int n_in,
                              void* d_out, int out_size, void* d_ws, size_t ws_size,
                              hipStream_t stream) {
    const float* x       = (const float*)d_in[0];
    const int*   ei      = (const int*)  d_in[1];
    const float* w1_rel  = (const float*)d_in[2];
    const float* w1_root = (const float*)d_in[3];
    const float* b1      = (const float*)d_in[4];
    const float* w2_rel  = (const float*)d_in[5];
    const float* w2_root = (const float*)d_in[6];
    const float* b2      = (const float*)d_in[7];
    float* out = (float*)d_out;

    // Workspace (~18.5 MB; everything rewritten each call):
    float*          agg   = (float*)d_ws;                                   // NROWS*16 f32 (6.4 MB)
    unsigned short* xrh   = (unsigned short*)(agg + (size_t)NROWS * D_HID); // NROWS*16 bf16 (3.2 MB)
    unsigned*       recs2 = (unsigned*)(xrh + (size_t)NROWS * D_HID);       // NB*PBC (8.0 MB)
    float*          hr    = (float*)(recs2 + (size_t)NB * PBC);             // NROWS*2 f32 (0.8 MB)
    int*            gcur  = (int*)(hr + (size_t)NROWS * D_OUT);             // NB

    hipMemsetAsync(gcur, 0, NB * sizeof(int), stream);

    k_bin_node1<<<dim3(BBLOCKS), dim3(512), 0, stream>>>(
        ei, x, w1_rel, w1_root, b1, xrh, agg, gcur, recs2);

    k_sortacc<<<dim3(NB), dim3(512), 0, stream>>>(
        gcur, recs2, xrh, agg, w2_rel, w2_root, b2, hr, out);

    k_acc2<<<dim3(ACC2_BLOCKS), dim3(256), 0, stream>>>(recs2, gcur, hr, out);
}